// Round 1
// baseline (572.871 us; speedup 1.0000x reference)
//
#include <hip/hip_runtime.h>
#include <hip/hip_bf16.h>

// Problem constants
#define BDIM 1024       // batch (M)
#define EDIM 512        // embed (K)
#define CDIM 70722      // classes (N)
#define NPAD 70784      // 553 * 128
#define SCALE 64.0f
#define EPS_C 1e-3f
#define M_COEF 0.4f
#define H_COEF 0.333f
#define PI_F 3.14159265358979323846f

using short8 = __attribute__((ext_vector_type(8))) short;
using f32x4  = __attribute__((ext_vector_type(4))) float;

__device__ __forceinline__ unsigned short f2bf(float f) {
    union { float f; unsigned int u; } x; x.f = f;
    unsigned int u = x.u;
    unsigned int r = (u + 0x7fffu + ((u >> 16) & 1u)) >> 16;   // RTNE
    return (unsigned short)r;
}

// ---------------------------------------------------------------------------
// Kernel 1: transpose + bf16 convert kernel (E x C f32) -> Bt (NPAD x E bf16),
// fused with per-column sum-of-squares accumulation (atomicAdd).
// Grid: (NPAD/64, EDIM/64), block 256.
// ---------------------------------------------------------------------------
__global__ __launch_bounds__(256) void convert_transpose(
        const float* __restrict__ Kw, unsigned short* __restrict__ Bt,
        float* __restrict__ colsumsq) {
    __shared__ float tile[64][65];
    __shared__ float ssq[4][64];
    const int t  = threadIdx.x;
    const int n0 = blockIdx.x * 64;
    const int k0 = blockIdx.y * 64;
    const int nn = t & 63;
    const int kg = t >> 6;

    float s = 0.f;
    const int ng = n0 + nn;
#pragma unroll
    for (int rr = 0; rr < 16; ++rr) {
        const int kk = kg * 16 + rr;
        float v = (ng < CDIM) ? Kw[(size_t)(k0 + kk) * CDIM + ng] : 0.f;
        tile[kk][nn] = v;
        s += v * v;
    }
    ssq[kg][nn] = s;
    __syncthreads();

    if (t < 64) {
        float tot = ssq[0][t] + ssq[1][t] + ssq[2][t] + ssq[3][t];
        if (n0 + t < CDIM) atomicAdd(&colsumsq[n0 + t], tot);
    }

    // transposed write: row = n, col = k (coalesced along k)
    const int k = t & 63;
    const int ngrp = t >> 6;
#pragma unroll
    for (int rr = 0; rr < 16; ++rr) {
        const int nl = ngrp * 16 + rr;
        float v = tile[k][nl];
        Bt[(size_t)(n0 + nl) * EDIM + k0 + k] = f2bf(v);
    }
}

// ---------------------------------------------------------------------------
// Kernel 2: inv_norm[n] = 1/sqrt(colsumsq[n])
// ---------------------------------------------------------------------------
__global__ __launch_bounds__(256) void inv_kernel(
        const float* __restrict__ colsumsq, float* __restrict__ inv_norm) {
    int n = blockIdx.x * 256 + threadIdx.x;
    if (n < NPAD) inv_norm[n] = (n < CDIM) ? (1.0f / sqrtf(colsumsq[n])) : 0.0f;
}

// ---------------------------------------------------------------------------
// Kernel 3: embeddings f32 -> bf16 (row-major M x K)
// ---------------------------------------------------------------------------
__global__ __launch_bounds__(256) void convert_A(
        const float* __restrict__ emb, unsigned short* __restrict__ Abf) {
    int i = (blockIdx.x * 256 + threadIdx.x) * 4;
    float4 v = *(const float4*)&emb[i];
    ushort4 o;
    o.x = f2bf(v.x); o.y = f2bf(v.y); o.z = f2bf(v.z); o.w = f2bf(v.w);
    *(ushort4*)&Abf[i] = o;
}

// ---------------------------------------------------------------------------
// Kernel 4: bf16 MFMA GEMM, m97 structure: 128x128 tile, BK=32, 4 waves (2x2),
// each wave 64x64 out (4x4 fragments of 16x16x32), global_load_lds width 16.
// Epilogue: cosine = acc * inv_norm[col]; clip; * SCALE.
// Grid: (NPAD/128, BDIM/128), block 256.
// ---------------------------------------------------------------------------
__global__ __launch_bounds__(256) void gemm_kernel(
        const unsigned short* __restrict__ A,   // 1024 x 512 bf16
        const unsigned short* __restrict__ Bt,  // NPAD x 512 bf16
        const float* __restrict__ inv_norm,
        float* __restrict__ out) {
    __shared__ unsigned short As[128 * 32];
    __shared__ unsigned short Bs[128 * 32];

    const int tid  = threadIdx.x;
    const int w    = tid >> 6;
    const int lane = tid & 63;
    const int wm   = w >> 1;      // 0..1
    const int wn   = w & 1;       // 0..1
    const int m0   = blockIdx.y * 128;
    const int n0   = blockIdx.x * 128;

    f32x4 acc[4][4] = {};

    const int lrow = lane & 15;
    const int koff = (lane >> 4) * 8;

    for (int kt = 0; kt < EDIM / 32; ++kt) {
        const int k0 = kt * 32;
        __syncthreads();   // previous iteration's LDS reads complete
#pragma unroll
        for (int j = 0; j < 2; ++j) {
            const int chunk = j * 256 + tid;         // 0..511 chunk of 8 bf16
            const int r = chunk >> 2;
            const int c = (chunk & 3) << 3;
            const unsigned short* ga = A  + (size_t)(m0 + r) * EDIM + (k0 + c);
            const unsigned short* gb = Bt + (size_t)(n0 + r) * EDIM + (k0 + c);
            char* la = (char*)As + (j * 4 + w) * 1024;   // wave-uniform base
            char* lb = (char*)Bs + (j * 4 + w) * 1024;
            __builtin_amdgcn_global_load_lds(
                (const __attribute__((address_space(1))) void*)ga,
                (__attribute__((address_space(3))) void*)la, 16, 0, 0);
            __builtin_amdgcn_global_load_lds(
                (const __attribute__((address_space(1))) void*)gb,
                (__attribute__((address_space(3))) void*)lb, 16, 0, 0);
        }
        asm volatile("s_waitcnt vmcnt(0)" ::: "memory");
        __syncthreads();

        short8 af[4], bf[4];
#pragma unroll
        for (int f = 0; f < 4; ++f) {
            af[f] = *(const short8*)&As[(wm * 64 + f * 16 + lrow) * 32 + koff];
            bf[f] = *(const short8*)&Bs[(wn * 64 + f * 16 + lrow) * 32 + koff];
        }
#pragma unroll
        for (int i = 0; i < 4; ++i)
#pragma unroll
            for (int jj = 0; jj < 4; ++jj)
                acc[i][jj] = __builtin_amdgcn_mfma_f32_16x16x32_bf16(
                    af[i], bf[jj], acc[i][jj], 0, 0, 0);
    }

    // Epilogue: D lane layout: col = lane&15, row = (lane>>4)*4 + reg
    const int colBase = n0 + wn * 64 + (lane & 15);
    const int rowBase = m0 + wm * 64 + (lane >> 4) * 4;
#pragma unroll
    for (int jj = 0; jj < 4; ++jj) {
        const int cg = colBase + jj * 16;
        if (cg < CDIM) {
            const float invn = inv_norm[cg];
#pragma unroll
            for (int i = 0; i < 4; ++i) {
#pragma unroll
                for (int r = 0; r < 4; ++r) {
                    const int rg = rowBase + i * 16 + r;
                    float v = acc[i][jj][r] * invn;
                    v = fminf(fmaxf(v, -1.0f + EPS_C), 1.0f - EPS_C);
                    out[(size_t)rg * CDIM + cg] = v * SCALE;
                }
            }
        }
    }
}

// ---------------------------------------------------------------------------
// Kernel 5: margin fixup on the label column of each row.
// One block of 1024 threads; block reduction for batch mean/std (ddof=1).
// ---------------------------------------------------------------------------
__global__ __launch_bounds__(1024) void fixup_kernel(
        const float* __restrict__ norms, const int* __restrict__ label,
        float* __restrict__ out) {
    __shared__ float red[1024];
    const int t = threadIdx.x;
    const float x = fminf(fmaxf(norms[t], 1e-3f), 100.0f);

    red[t] = x;
    __syncthreads();
#pragma unroll
    for (int s = 512; s > 0; s >>= 1) {
        if (t < s) red[t] += red[t + s];
        __syncthreads();
    }
    const float mean = red[0] * (1.0f / 1024.0f);
    __syncthreads();

    const float d = x - mean;
    red[t] = d * d;
    __syncthreads();
#pragma unroll
    for (int s = 512; s > 0; s >>= 1) {
        if (t < s) red[t] += red[t + s];
        __syncthreads();
    }
    const float stdv = sqrtf(red[0] * (1.0f / 1023.0f));   // ddof=1

    float ms = (x - mean) / (stdv + EPS_C) * H_COEF;
    ms = fminf(fmaxf(ms, -1.0f), 1.0f);
    const float g_ang = -M_COEF * ms;
    const float g_add = M_COEF + M_COEF * ms;

    const size_t idx = (size_t)t * CDIM + label[t];
    const float c = out[idx] * (1.0f / SCALE);   // stored = SCALE * clipped cosine
    float theta = acosf(c) + g_ang;
    theta = fminf(fmaxf(theta, EPS_C), PI_F - EPS_C);
    out[idx] = (cosf(theta) - g_add) * SCALE;
}

// ---------------------------------------------------------------------------
extern "C" void kernel_launch(void* const* d_in, const int* in_sizes, int n_in,
                              void* d_out, int out_size, void* d_ws, size_t ws_size,
                              hipStream_t stream) {
    const float* emb   = (const float*)d_in[0];
    const float* norms = (const float*)d_in[1];
    const int*   label = (const int*)d_in[2];
    const float* Kw    = (const float*)d_in[3];
    float* out = (float*)d_out;

    char* ws = (char*)d_ws;
    // layout: colsumsq [NPAD f32] | inv_norm [NPAD f32] | Abf [1024*512 bf16] | Bt [NPAD*512 bf16]
    float* colsumsq          = (float*)(ws + 0);
    float* inv_norm          = (float*)(ws + 283136);
    unsigned short* Abf      = (unsigned short*)(ws + 566272);
    unsigned short* Bt       = (unsigned short*)(ws + 1614848);

    hipMemsetAsync(colsumsq, 0, NPAD * sizeof(float), stream);

    convert_transpose<<<dim3(NPAD / 64, EDIM / 64), 256, 0, stream>>>(Kw, Bt, colsumsq);
    inv_kernel<<<dim3((NPAD + 255) / 256), 256, 0, stream>>>(colsumsq, inv_norm);
    convert_A<<<dim3(BDIM * EDIM / (256 * 4)), 256, 0, stream>>>(emb, Abf);
    gemm_kernel<<<dim3(NPAD / 128, BDIM / 128), 256, 0, stream>>>(Abf, Bt, inv_norm, out);
    fixup_kernel<<<1, 1024, 0, stream>>>(norms, label, out);
}